// Round 9
// baseline (434.147 us; speedup 1.0000x reference)
//
#include <hip/hip_runtime.h>

#define N_NODES 16384
#define N_EDGES 262144
#define BATCH   256
#define F_OUT   32
#define K_ORD   4
#define NCHUNK  8      // batch chunks == XCD count
#define CHUNK   32     // batch lanes per chunk
#define NPB     8      // nodes per iteration (8 nodes x 32 lanes = 256 thr)
#define GRID_P  2048   // persistent blocks: 8/CU x 256 CU
#define NGRP    (N_NODES / NPB)          // 2048 node groups
#define GPB     (NGRP / (GRID_P / NCHUNK))  // 8 groups per block

typedef float f32x4 __attribute__((ext_vector_type(4)));

// ---------------- transpose: x (B,N) -> xT (N,B) ----------------
__global__ void transpose_kernel(const float* __restrict__ x, float* __restrict__ xT) {
    __shared__ float tile[32][33];
    int tx = threadIdx.x;          // 0..31
    int ty = threadIdx.y;          // 0..7
    int n0 = blockIdx.x * 32;
    int b0 = blockIdx.y * 32;
#pragma unroll
    for (int j = 0; j < 4; ++j) {
        int b = b0 + ty + j * 8;
        int n = n0 + tx;
        tile[ty + j * 8][tx] = x[(size_t)b * N_NODES + n];
    }
    __syncthreads();
#pragma unroll
    for (int j = 0; j < 4; ++j) {
        int n = n0 + ty + j * 8;
        int b = b0 + tx;
        xT[(size_t)n * BATCH + b] = tile[tx][ty + j * 8];
    }
}

// ---------------- CSR build ----------------
__global__ void hist_kernel(const int* __restrict__ rows, int* __restrict__ count) {
    int e = blockIdx.x * blockDim.x + threadIdx.x;
    if (e < N_EDGES) atomicAdd(&count[rows[e]], 1);
}

__global__ void scan_kernel(int* __restrict__ count, int* __restrict__ row_ptr) {
    __shared__ int part[256];
    int t = threadIdx.x;
    int base = t * 64;
    int loc[64];
    int s = 0;
#pragma unroll
    for (int i = 0; i < 64; ++i) { loc[i] = count[base + i]; s += loc[i]; }
    part[t] = s;
    __syncthreads();
    for (int d = 1; d < 256; d <<= 1) {
        int v = (t >= d) ? part[t - d] : 0;
        __syncthreads();
        part[t] += v;
        __syncthreads();
    }
    int off = part[t] - s;  // exclusive prefix
#pragma unroll
    for (int i = 0; i < 64; ++i) {
        row_ptr[base + i] = off;
        count[base + i] = off;   // becomes the scatter cursor
        off += loc[i];
    }
    if (t == 255) row_ptr[N_NODES] = off;   // == N_EDGES
}

__global__ void scatter_kernel(const int* __restrict__ rows, const int* __restrict__ cols,
                               const float* __restrict__ vals,
                               int* __restrict__ cursor,
                               int* __restrict__ csr_col, float* __restrict__ csr_val) {
    int e = blockIdx.x * blockDim.x + threadIdx.x;
    if (e < N_EDGES) {
        int r = rows[e];
        int pos = atomicAdd(&cursor[r], 1);
        csr_col[pos] = cols[e];
        csr_val[pos] = vals[e];
    }
}

// ---------------- Chebyshev step, persistent XCD-chunked, NT streams ----------------
// Gather loads (in[]) cacheable; all single-use streams (csr, prev) nontemporal so the
// 2MB batch-slice stays resident in the XCD's 4MB L2.
__global__ void __launch_bounds__(256, 8)
cheb_kernel(const float* __restrict__ in, const float* __restrict__ prev,
            float* __restrict__ out,
            const int* __restrict__ row_ptr,
            const float* __restrict__ csr_val, const int* __restrict__ csr_col,
            float c) {
    int chunk = blockIdx.x & (NCHUNK - 1);
    int bslot = blockIdx.x >> 3;               // 0..255
    int nsub  = threadIdx.x >> 5;
    int b     = chunk * CHUNK + (threadIdx.x & 31);
    for (int g = 0; g < GPB; ++g) {
        int n = (bslot + g * 256) * NPB + nsub;
        int beg = row_ptr[n], end = row_ptr[n + 1];
        float acc = 0.f;
        int e = beg;
        for (; e + 3 < end; e += 4) {
            int   c0 = __builtin_nontemporal_load(&csr_col[e]);
            int   c1 = __builtin_nontemporal_load(&csr_col[e + 1]);
            int   c2 = __builtin_nontemporal_load(&csr_col[e + 2]);
            int   c3 = __builtin_nontemporal_load(&csr_col[e + 3]);
            float v0 = __builtin_nontemporal_load(&csr_val[e]);
            float v1 = __builtin_nontemporal_load(&csr_val[e + 1]);
            float v2 = __builtin_nontemporal_load(&csr_val[e + 2]);
            float v3 = __builtin_nontemporal_load(&csr_val[e + 3]);
            acc += v0 * in[(size_t)c0 * BATCH + b];
            acc += v1 * in[(size_t)c1 * BATCH + b];
            acc += v2 * in[(size_t)c2 * BATCH + b];
            acc += v3 * in[(size_t)c3 * BATCH + b];
        }
        for (; e < end; ++e) {
            int   cc = __builtin_nontemporal_load(&csr_col[e]);
            float vv = __builtin_nontemporal_load(&csr_val[e]);
            acc += vv * in[(size_t)cc * BATCH + b];
        }
        size_t idx = (size_t)n * BATCH + b;
        float o = c * (acc - in[idx]);
        if (prev) o -= __builtin_nontemporal_load(&prev[idx]);
        out[idx] = o;
    }
}

// ---------------- fused final, persistent XCD-chunked, NT streams ----------------
__global__ void __launch_bounds__(256, 8)
final_kernel(const float* __restrict__ t0, const float* __restrict__ t1,
             const float* __restrict__ t2,
             const int* __restrict__ row_ptr,
             const float* __restrict__ csr_val, const int* __restrict__ csr_col,
             const float* __restrict__ weight, const float* __restrict__ bias,
             float* __restrict__ out) {
    __shared__ float w[F_OUT * K_ORD];
    __shared__ float bb[F_OUT];
    __shared__ f32x4 tval[NPB][CHUNK];
    int tid = threadIdx.x;
    if (tid < F_OUT * K_ORD) w[tid] = weight[tid];
    if (tid < F_OUT) bb[tid] = bias[tid];
    __syncthreads();

    int chunk = blockIdx.x & (NCHUNK - 1);
    int bslot = blockIdx.x >> 3;

    // phase-1 thread mapping
    int p1_nsub = tid >> 5;
    int p1_bi   = tid & 31;
    int p1_b    = chunk * CHUNK + p1_bi;
    // phase-2 thread mapping (f const per thread -> weights in registers)
    int f = (tid & 7) * 4;
    f32x4 w0 = *(const f32x4*)&w[(f + 0) * 4];
    f32x4 w1 = *(const f32x4*)&w[(f + 1) * 4];
    f32x4 w2 = *(const f32x4*)&w[(f + 2) * 4];
    f32x4 w3 = *(const f32x4*)&w[(f + 3) * 4];
    f32x4 b4 = *(const f32x4*)&bb[f];
    int p2_nsub = (tid >> 3) & 7;
    int p2_wv   = tid >> 6;

    for (int g = 0; g < GPB; ++g) {
        int ng = bslot + g * 256;
        {
            int n = ng * NPB + p1_nsub;
            int beg = row_ptr[n], end = row_ptr[n + 1];
            float acc = 0.f;
            int e = beg;
            for (; e + 3 < end; e += 4) {
                int   c0 = __builtin_nontemporal_load(&csr_col[e]);
                int   c1 = __builtin_nontemporal_load(&csr_col[e + 1]);
                int   c2 = __builtin_nontemporal_load(&csr_col[e + 2]);
                int   c3 = __builtin_nontemporal_load(&csr_col[e + 3]);
                float v0 = __builtin_nontemporal_load(&csr_val[e]);
                float v1 = __builtin_nontemporal_load(&csr_val[e + 1]);
                float v2 = __builtin_nontemporal_load(&csr_val[e + 2]);
                float v3 = __builtin_nontemporal_load(&csr_val[e + 3]);
                acc += v0 * t2[(size_t)c0 * BATCH + p1_b];
                acc += v1 * t2[(size_t)c1 * BATCH + p1_b];
                acc += v2 * t2[(size_t)c2 * BATCH + p1_b];
                acc += v3 * t2[(size_t)c3 * BATCH + p1_b];
            }
            for (; e < end; ++e) {
                int   cc = __builtin_nontemporal_load(&csr_col[e]);
                float vv = __builtin_nontemporal_load(&csr_val[e]);
                acc += vv * t2[(size_t)cc * BATCH + p1_b];
            }

            size_t idx = (size_t)n * BATCH + p1_b;
            float t2v = t2[idx];
            float t3v = 2.f * (acc - t2v) - __builtin_nontemporal_load(&t1[idx]);
            float t0v = __builtin_nontemporal_load(&t0[idx]);
            float t1v = __builtin_nontemporal_load(&t1[idx]);
            tval[p1_nsub][p1_bi] = (f32x4){t0v, t1v, t2v, t3v};
        }
        __syncthreads();

        size_t n = (size_t)(ng * NPB + p2_nsub);
#pragma unroll
        for (int i = 0; i < 8; ++i) {
            int b_idx = i * 4 + p2_wv;                   // 0..31
            size_t b  = (size_t)(chunk * CHUNK + b_idx);
            f32x4 tv = tval[p2_nsub][b_idx];
            f32x4 r;
            r.x = w0.x * tv.x + w0.y * tv.y + w0.z * tv.z + w0.w * tv.w + b4.x;
            r.y = w1.x * tv.x + w1.y * tv.y + w1.z * tv.z + w1.w * tv.w + b4.y;
            r.z = w2.x * tv.x + w2.y * tv.y + w2.z * tv.z + w2.w * tv.w + b4.z;
            r.w = w3.x * tv.x + w3.y * tv.y + w3.z * tv.z + w3.w * tv.w + b4.w;
            __builtin_nontemporal_store(r, (f32x4*)(out + (b * N_NODES + n) * F_OUT + f));
        }
        __syncthreads();   // protect tval before next iteration overwrites
    }
}

extern "C" void kernel_launch(void* const* d_in, const int* in_sizes, int n_in,
                              void* d_out, int out_size, void* d_ws, size_t ws_size,
                              hipStream_t stream) {
    const float* x      = (const float*)d_in[0];
    const float* vals   = (const float*)d_in[1];
    const int*   rows   = (const int*)d_in[2];
    const int*   cols   = (const int*)d_in[3];
    const float* weight = (const float*)d_in[4];
    const float* bias   = (const float*)d_in[5];
    float* out = (float*)d_out;

    const size_t NB = (size_t)N_NODES * BATCH;   // 4,194,304 floats
    float* xT      = (float*)d_ws;
    float* t1      = xT + NB;
    float* t2      = t1 + NB;
    int*   row_ptr = (int*)(t2 + NB);            // N_NODES+1 (pad to 16448)
    int*   cursor  = row_ptr + 16448;            // N_NODES ints; also the histogram
    float* csr_val = (float*)(cursor + N_NODES);
    int*   csr_col = (int*)(csr_val + N_EDGES);

    (void)hipMemsetAsync(cursor, 0, N_NODES * sizeof(int), stream);

    transpose_kernel<<<dim3(N_NODES / 32, BATCH / 32), dim3(32, 8), 0, stream>>>(x, xT);
    hist_kernel<<<N_EDGES / 256, 256, 0, stream>>>(rows, cursor);
    scan_kernel<<<1, 256, 0, stream>>>(cursor, row_ptr);
    scatter_kernel<<<N_EDGES / 256, 256, 0, stream>>>(rows, cols, vals, cursor, csr_col, csr_val);

    cheb_kernel<<<GRID_P, 256, 0, stream>>>(xT, nullptr, t1, row_ptr, csr_val, csr_col, 1.f);
    cheb_kernel<<<GRID_P, 256, 0, stream>>>(t1, xT, t2, row_ptr, csr_val, csr_col, 2.f);
    final_kernel<<<GRID_P, 256, 0, stream>>>(xT, t1, t2, row_ptr, csr_val, csr_col,
                                             weight, bias, out);
}

// Round 10
// 214.412 us; speedup vs baseline: 2.0248x; 2.0248x over previous
//
#include <hip/hip_runtime.h>

#define N_NODES 16384
#define N_EDGES 262144
#define BATCH   256
#define F_OUT   32
#define K_ORD   4
#define NCHUNK  4      // batch chunks; 64 b-lanes each -> full 128B bf16 gather lines
#define CHUNK   64
#define NPB     8      // nodes per block

typedef float f32x4 __attribute__((ext_vector_type(4)));
typedef float f32x2 __attribute__((ext_vector_type(2)));

__device__ __forceinline__ unsigned short f2bf(float f) {
    unsigned u = __float_as_uint(f);
    return (unsigned short)((u + 0x7FFFu + ((u >> 16) & 1u)) >> 16);
}
__device__ __forceinline__ float bf2f(unsigned v) {   // low 16 bits
    return __uint_as_float(v << 16);
}

// ---------------- transpose: x (B,N) -> xT f32 (N,B) + xb bf16 (N,B) ----------------
__global__ void transpose_kernel(const float* __restrict__ x, float* __restrict__ xT,
                                 unsigned short* __restrict__ xb) {
    __shared__ float tile[32][33];
    int tx = threadIdx.x;          // 0..31
    int ty = threadIdx.y;          // 0..7
    int n0 = blockIdx.x * 32;
    int b0 = blockIdx.y * 32;
#pragma unroll
    for (int j = 0; j < 4; ++j) {
        int b = b0 + ty + j * 8;
        int n = n0 + tx;
        tile[ty + j * 8][tx] = x[(size_t)b * N_NODES + n];
    }
    __syncthreads();
#pragma unroll
    for (int j = 0; j < 4; ++j) {
        int n = n0 + ty + j * 8;
        int b = b0 + tx;
        float v = tile[tx][ty + j * 8];
        xT[(size_t)n * BATCH + b] = v;
        xb[(size_t)n * BATCH + b] = f2bf(v);
    }
}

// ---------------- CSR build (packed: low16 = col, high16 = bf16 val) ----------------
__global__ void hist_kernel(const int* __restrict__ rows, int* __restrict__ count) {
    int e = blockIdx.x * blockDim.x + threadIdx.x;
    if (e < N_EDGES) atomicAdd(&count[rows[e]], 1);
}

__global__ void scan_kernel(int* __restrict__ count, int* __restrict__ row_ptr) {
    __shared__ int part[256];
    int t = threadIdx.x;
    int base = t * 64;
    int loc[64];
    int s = 0;
#pragma unroll
    for (int i = 0; i < 64; ++i) { loc[i] = count[base + i]; s += loc[i]; }
    part[t] = s;
    __syncthreads();
    for (int d = 1; d < 256; d <<= 1) {
        int v = (t >= d) ? part[t - d] : 0;
        __syncthreads();
        part[t] += v;
        __syncthreads();
    }
    int off = part[t] - s;  // exclusive prefix
#pragma unroll
    for (int i = 0; i < 64; ++i) {
        row_ptr[base + i] = off;
        count[base + i] = off;   // becomes the scatter cursor
        off += loc[i];
    }
    if (t == 255) row_ptr[N_NODES] = off;   // == N_EDGES
}

__global__ void scatter_kernel(const int* __restrict__ rows, const int* __restrict__ cols,
                               const float* __restrict__ vals,
                               int* __restrict__ cursor,
                               unsigned* __restrict__ csrp) {
    int e = blockIdx.x * blockDim.x + threadIdx.x;
    if (e < N_EDGES) {
        int r = rows[e];
        int pos = atomicAdd(&cursor[r], 1);
        csrp[pos] = (unsigned)cols[e] | ((unsigned)f2bf(vals[e]) << 16);
    }
}

// ---------------- Chebyshev step: out = c*(L@in - in) - prev ----------------
// bf16 gather operand (inb), f32 state. Block: 8 nodes x 32 lanes, 2 b per lane.
__global__ void cheb_kernel(const float* __restrict__ in, const unsigned short* __restrict__ inb,
                            const float* __restrict__ prev,
                            float* __restrict__ out, unsigned short* __restrict__ outb,
                            const int* __restrict__ row_ptr,
                            const unsigned* __restrict__ csrp, float c) {
    int chunk = blockIdx.x & (NCHUNK - 1);
    int ng    = blockIdx.x >> 2;
    int nsub  = threadIdx.x >> 5;
    int b     = chunk * CHUNK + (threadIdx.x & 31) * 2;
    int n     = ng * NPB + nsub;
    int beg = row_ptr[n], end = row_ptr[n + 1];
    f32x2 acc = (f32x2)(0.f);
    int e = beg;
    for (; e + 3 < end; e += 4) {
        unsigned p0 = csrp[e], p1 = csrp[e + 1], p2 = csrp[e + 2], p3 = csrp[e + 3];
        unsigned g0 = *(const unsigned*)&inb[(size_t)(p0 & 0xFFFF) * BATCH + b];
        unsigned g1 = *(const unsigned*)&inb[(size_t)(p1 & 0xFFFF) * BATCH + b];
        unsigned g2 = *(const unsigned*)&inb[(size_t)(p2 & 0xFFFF) * BATCH + b];
        unsigned g3 = *(const unsigned*)&inb[(size_t)(p3 & 0xFFFF) * BATCH + b];
        float v0 = bf2f(p0 >> 16), v1 = bf2f(p1 >> 16), v2 = bf2f(p2 >> 16), v3 = bf2f(p3 >> 16);
        acc.x += v0 * bf2f(g0 & 0xFFFF) + v1 * bf2f(g1 & 0xFFFF)
               + v2 * bf2f(g2 & 0xFFFF) + v3 * bf2f(g3 & 0xFFFF);
        acc.y += v0 * bf2f(g0 >> 16) + v1 * bf2f(g1 >> 16)
               + v2 * bf2f(g2 >> 16) + v3 * bf2f(g3 >> 16);
    }
    for (; e < end; ++e) {
        unsigned p = csrp[e];
        unsigned g = *(const unsigned*)&inb[(size_t)(p & 0xFFFF) * BATCH + b];
        float v = bf2f(p >> 16);
        acc.x += v * bf2f(g & 0xFFFF);
        acc.y += v * bf2f(g >> 16);
    }
    size_t idx = (size_t)n * BATCH + b;
    f32x2 self = *(const f32x2*)&in[idx];
    f32x2 o = c * (acc - self);
    if (prev) o -= *(const f32x2*)&prev[idx];
    *(f32x2*)&out[idx] = o;
    *(unsigned*)&outb[idx] = (unsigned)f2bf(o.x) | ((unsigned)f2bf(o.y) << 16);
}

// ---------------- fused final: T3 = 2*(L@T2 - T2) - T1 ; y = [T0..T3] @ W^T + b ------
__global__ void final_kernel(const float* __restrict__ t0, const float* __restrict__ t1,
                             const float* __restrict__ t2, const unsigned short* __restrict__ t2b,
                             const int* __restrict__ row_ptr,
                             const unsigned* __restrict__ csrp,
                             const float* __restrict__ weight, const float* __restrict__ bias,
                             float* __restrict__ out) {
    __shared__ float w[F_OUT * K_ORD];
    __shared__ float bb[F_OUT];
    __shared__ f32x4 tval[NPB][CHUNK + 1];   // pad -> phase-2 reads spread banks
    int tid = threadIdx.x;
    if (tid < F_OUT * K_ORD) w[tid] = weight[tid];
    if (tid < F_OUT) bb[tid] = bias[tid];
    __syncthreads();

    int chunk = blockIdx.x & (NCHUNK - 1);
    int ng    = blockIdx.x >> 2;
    {
        int nsub = tid >> 5;
        int bi   = (tid & 31) * 2;
        int b    = chunk * CHUNK + bi;
        int n    = ng * NPB + nsub;
        int beg = row_ptr[n], end = row_ptr[n + 1];
        f32x2 acc = (f32x2)(0.f);
        int e = beg;
        for (; e + 3 < end; e += 4) {
            unsigned p0 = csrp[e], p1 = csrp[e + 1], p2 = csrp[e + 2], p3 = csrp[e + 3];
            unsigned g0 = *(const unsigned*)&t2b[(size_t)(p0 & 0xFFFF) * BATCH + b];
            unsigned g1 = *(const unsigned*)&t2b[(size_t)(p1 & 0xFFFF) * BATCH + b];
            unsigned g2 = *(const unsigned*)&t2b[(size_t)(p2 & 0xFFFF) * BATCH + b];
            unsigned g3 = *(const unsigned*)&t2b[(size_t)(p3 & 0xFFFF) * BATCH + b];
            float v0 = bf2f(p0 >> 16), v1 = bf2f(p1 >> 16), v2 = bf2f(p2 >> 16), v3 = bf2f(p3 >> 16);
            acc.x += v0 * bf2f(g0 & 0xFFFF) + v1 * bf2f(g1 & 0xFFFF)
                   + v2 * bf2f(g2 & 0xFFFF) + v3 * bf2f(g3 & 0xFFFF);
            acc.y += v0 * bf2f(g0 >> 16) + v1 * bf2f(g1 >> 16)
                   + v2 * bf2f(g2 >> 16) + v3 * bf2f(g3 >> 16);
        }
        for (; e < end; ++e) {
            unsigned p = csrp[e];
            unsigned g = *(const unsigned*)&t2b[(size_t)(p & 0xFFFF) * BATCH + b];
            float v = bf2f(p >> 16);
            acc.x += v * bf2f(g & 0xFFFF);
            acc.y += v * bf2f(g >> 16);
        }
        size_t idx = (size_t)n * BATCH + b;
        f32x2 t2v = *(const f32x2*)&t2[idx];
        f32x2 t1v = *(const f32x2*)&t1[idx];
        f32x2 t0v = *(const f32x2*)&t0[idx];
        f32x2 t3v = 2.f * (acc - t2v) - t1v;
        tval[nsub][bi]     = (f32x4){t0v.x, t1v.x, t2v.x, t3v.x};
        tval[nsub][bi + 1] = (f32x4){t0v.y, t1v.y, t2v.y, t3v.y};
    }
    __syncthreads();

    // phase 2: 8 nodes x 64 b x 32 f floats = 4096 f32x4; 16 per thread.
    // At fixed i a wave covers nsub 0..7 x f 0..31 -> 1KB contiguous per store.
    int f = (tid & 7) * 4;
    f32x4 w0 = *(const f32x4*)&w[(f + 0) * 4];
    f32x4 w1 = *(const f32x4*)&w[(f + 1) * 4];
    f32x4 w2 = *(const f32x4*)&w[(f + 2) * 4];
    f32x4 w3 = *(const f32x4*)&w[(f + 3) * 4];
    f32x4 b4 = *(const f32x4*)&bb[f];
    int nsub = (tid >> 3) & 7;
    int wv   = tid >> 6;
    size_t n = (size_t)(ng * NPB + nsub);
#pragma unroll
    for (int i = 0; i < 16; ++i) {
        int b_idx = i * 4 + wv;                      // 0..63
        size_t b  = (size_t)(chunk * CHUNK + b_idx);
        f32x4 tv = tval[nsub][b_idx];
        f32x4 r;
        r.x = w0.x * tv.x + w0.y * tv.y + w0.z * tv.z + w0.w * tv.w + b4.x;
        r.y = w1.x * tv.x + w1.y * tv.y + w1.z * tv.z + w1.w * tv.w + b4.y;
        r.z = w2.x * tv.x + w2.y * tv.y + w2.z * tv.z + w2.w * tv.w + b4.z;
        r.w = w3.x * tv.x + w3.y * tv.y + w3.z * tv.z + w3.w * tv.w + b4.w;
        __builtin_nontemporal_store(r, (f32x4*)(out + (b * N_NODES + n) * F_OUT + f));
    }
}

extern "C" void kernel_launch(void* const* d_in, const int* in_sizes, int n_in,
                              void* d_out, int out_size, void* d_ws, size_t ws_size,
                              hipStream_t stream) {
    const float* x      = (const float*)d_in[0];
    const float* vals   = (const float*)d_in[1];
    const int*   rows   = (const int*)d_in[2];
    const int*   cols   = (const int*)d_in[3];
    const float* weight = (const float*)d_in[4];
    const float* bias   = (const float*)d_in[5];
    float* out = (float*)d_out;

    const size_t NB = (size_t)N_NODES * BATCH;   // 4,194,304 elements
    float*          xT      = (float*)d_ws;
    float*          t1      = xT + NB;
    float*          t2      = t1 + NB;
    unsigned short* xb      = (unsigned short*)(t2 + NB);
    unsigned short* t1b     = xb + NB;
    unsigned short* t2b     = t1b + NB;
    int*            row_ptr = (int*)(t2b + NB);  // N_NODES+1 (pad to 16448)
    int*            cursor  = row_ptr + 16448;
    unsigned*       csrp    = (unsigned*)(cursor + N_NODES);

    (void)hipMemsetAsync(cursor, 0, N_NODES * sizeof(int), stream);

    transpose_kernel<<<dim3(N_NODES / 32, BATCH / 32), dim3(32, 8), 0, stream>>>(x, xT, xb);
    hist_kernel<<<N_EDGES / 256, 256, 0, stream>>>(rows, cursor);
    scan_kernel<<<1, 256, 0, stream>>>(cursor, row_ptr);
    scatter_kernel<<<N_EDGES / 256, 256, 0, stream>>>(rows, cols, vals, cursor, csrp);

    const int GRID = (N_NODES / NPB) * NCHUNK;   // 8192 blocks
    cheb_kernel<<<GRID, 256, 0, stream>>>(xT, xb, nullptr, t1, t1b, row_ptr, csrp, 1.f);
    cheb_kernel<<<GRID, 256, 0, stream>>>(t1, t1b, xT, t2, t2b, row_ptr, csrp, 2.f);
    final_kernel<<<GRID, 256, 0, stream>>>(xT, t1, t2, t2b, row_ptr, csrp,
                                           weight, bias, out);
}